// Round 8
// baseline (58.947 us; speedup 1.0000x reference)
//
#include <hip/hip_runtime.h>

#define NB 8
#define ICN 64
#define NC 64
#define H 56
#define W 56
#define HW (H*W)
#define PH 58
#define PW 58
#define PHW (PH*PW)   // 3364

typedef __attribute__((ext_vector_type(8))) _Float16 half8;

// ---------- fused setup: prep params + transpose/pad/convert x ----------
__global__ __launch_bounds__(256) void setup_kernel(
    const float* __restrict__ x, const float* __restrict__ geo,
    const float* __restrict__ lin,
    _Float16* __restrict__ xt, float* __restrict__ prm)
{
    const int bx = blockIdx.x;
    if (bx < 64) {
        const int i = bx * 256 + threadIdx.x;        // c*ICN + ic, 16384 exact
        const float t00 = geo[i*6+0], t01 = geo[i*6+1], t02 = geo[i*6+2];
        const float t10 = geo[i*6+3], t11 = geo[i*6+4], t12 = geo[i*6+5];
        prm[i*8+0] = t00;
        prm[i*8+1] = t01;
        prm[i*8+2] = -27.5f*(t00+t01) + 28.f*t02 + 27.5f;
        prm[i*8+3] = t10;
        prm[i*8+4] = t11;
        prm[i*8+5] = -27.5f*(t10+t11) + 28.f*t12 + 27.5f;
        prm[i*8+6] = lin[i];
        prm[i*8+7] = 0.f;
    } else {
        const int id = (bx - 64) * 256 + threadIdx.x;   // ic*PHW + ph*PW + pw, 215296 exact
        const int ic  = id / PHW;
        const int rem = id - ic * PHW;
        const int ph  = rem / PW;
        const int pw  = rem - ph * PW;
        half8 v;
        #pragma unroll
        for (int b = 0; b < NB; ++b) v[b] = (_Float16)0.f;
        if (ph >= 1 && ph <= H && pw >= 1 && pw <= W) {
            const int p = (ph - 1) * W + (pw - 1);
            #pragma unroll
            for (int b = 0; b < NB; ++b)
                v[b] = (_Float16)x[(size_t)b * ICN * HW + ic * HW + p];
        }
        *(half8*)(xt + (size_t)id * NB) = v;
    }
}

__device__ __forceinline__ float box_factor(const float* bp, float wf, float hf) {
    const float xs = 2.0f * (wf + 0.5f) / (float)W - 1.0f;
    const float ys = 2.0f * (hf + 0.5f) / (float)H - 1.0f;
    const float gx = bp[0]*xs + bp[1]*ys + bp[2];
    const float gy = bp[3]*xs + bp[4]*ys + bp[5];
    const float ixf = ((gx + 1.f)*(float)W - 1.f) * 0.5f;
    const float iyf = ((gy + 1.f)*(float)H - 1.f) * 0.5f;
    const float ix0 = floorf(ixf), iy0 = floorf(iyf);
    const float fx = ixf - ix0, fy = iyf - iy0;
    const int cx0 = (int)ix0, cy0 = (int)iy0;
    const int cx1 = cx0 + 1,  cy1 = cy0 + 1;
    const bool vx0 = (cx0 >= 0) && (cx0 < W);
    const bool vx1 = (cx1 >= 0) && (cx1 < W);
    const bool vy0 = (cy0 >= 0) && (cy0 < H);
    const bool vy1 = (cy1 >= 0) && (cy1 < H);
    return (1.f-fx)*(1.f-fy)*((vx0 && vy0) ? 1.f : 0.f)
         + (1.f-fx)*fy     *((vx0 && vy1) ? 1.f : 0.f)
         + fx*(1.f-fy)     *((vx1 && vy0) ? 1.f : 0.f)
         + fx*fy           *((vx1 && vy1) ? 1.f : 0.f);
}

// ---------- main: thread owns (c, px-pair (h,w)&(h+1,w)), all 8 batches ----------
// Vertical pairs share the bilinear footprint: bottom pixel's source window is
// usually the top window shifted one row -> 6 loads per pair instead of 8.
__global__ __launch_bounds__(128) void geom_p_kernel(
    const _Float16* __restrict__ xt, // (IC, 58, 58, B)
    const float* __restrict__ prm,   // (C, IC, 8) folded params
    const float* __restrict__ boxp,  // (C, 2, 3)
    float* __restrict__ out)         // (B, C, H, W)
{
    const int c   = blockIdx.x;
    const int idx = blockIdx.y * 128 + threadIdx.x;  // 13 blocks * 128 = 1664 >= 1568
    const int h2  = idx / W;                          // row-pair index 0..27
    const int w   = idx - h2 * W;
    if (h2 >= H/2) return;
    const float wf = (float)w, hf = (float)(2*h2);

    float accT[NB], accB[NB];
    #pragma unroll
    for (int b = 0; b < NB; ++b) { accT[b] = 0.f; accB[b] = 0.f; }

    const float* pp = prm + (size_t)c * ICN * 8;

    for (int icc = 0; icc < ICN; icc += 4) {
        half8 haccT, haccB;
        #pragma unroll
        for (int b = 0; b < NB; ++b) { haccT[b] = (_Float16)0.f; haccB[b] = (_Float16)0.f; }

        #pragma unroll
        for (int k = 0; k < 4; ++k) {
            const float* q = pp + (icc + k) * 8;     // block-uniform -> s_load
            const float Bx = q[1], By = q[4];
            const float ixf = fmaf(q[0], wf, fmaf(Bx, hf, q[2]));
            const float iyf = fmaf(q[3], wf, fmaf(By, hf, q[5]));
            const float l   = q[6];
            const float ixf2 = ixf + Bx;             // bottom pixel (h+1)
            const float iyf2 = iyf + By;

            const float fcx0 = fminf(fmaxf(floorf(ixf),  -1.f), 55.f);
            const float fcy0 = fminf(fmaxf(floorf(iyf),  -1.f), 55.f);
            const float fcx2 = fminf(fmaxf(floorf(ixf2), -1.f), 55.f);
            const float fcy2 = fminf(fmaxf(floorf(iyf2), -1.f), 55.f);

            // top-pixel weights (linComb folded into y-weights)
            const float wx0 = fmaxf(0.f, 1.f - fabsf(ixf - fcx0));
            const float wx1 = fmaxf(0.f, 1.f - fabsf(ixf - fcx0 - 1.f));
            const float wy0 = fmaxf(0.f, 1.f - fabsf(iyf - fcy0)) * l;
            const float wy1 = fmaxf(0.f, 1.f - fabsf(iyf - fcy0 - 1.f)) * l;
            const _Float16 hw00 = (_Float16)(wx0*wy0), hw10 = (_Float16)(wx1*wy0);
            const _Float16 hw01 = (_Float16)(wx0*wy1), hw11 = (_Float16)(wx1*wy1);

            // bottom-pixel weights
            const float bx0 = fmaxf(0.f, 1.f - fabsf(ixf2 - fcx2));
            const float bx1 = fmaxf(0.f, 1.f - fabsf(ixf2 - fcx2 - 1.f));
            const float by0 = fmaxf(0.f, 1.f - fabsf(iyf2 - fcy2)) * l;
            const float by1 = fmaxf(0.f, 1.f - fabsf(iyf2 - fcy2 - 1.f)) * l;
            const _Float16 hb00 = (_Float16)(bx0*by0), hb10 = (_Float16)(bx1*by0);
            const _Float16 hb01 = (_Float16)(bx0*by1), hb11 = (_Float16)(bx1*by1);

            const int ix0 = (int)fcx0, iy0 = (int)fcy0;
            const _Float16* base =
                xt + ((size_t)(icc + k) * PHW + (iy0 + 1) * PW + ix0 + 1) * NB;

            const half8 v00 = *(const half8*)(base);
            const half8 v10 = *(const half8*)(base + NB);
            const half8 v01 = *(const half8*)(base + PW * NB);
            const half8 v11 = *(const half8*)(base + (PW + 1) * NB);
            haccT += v00 * hw00 + v10 * hw10 + v01 * hw01 + v11 * hw11;

            // bottom pixel: reuse v01/v11 + one new row when windows chain
            half8 a00 = v01, a10 = v11, a01, a11;
            const bool common = (fcx2 == fcx0) && (fcy2 == fcy0 + 1.f);
            if (common) {
                a01 = *(const half8*)(base + 2 * PW * NB);
                a11 = *(const half8*)(base + (2 * PW + 1) * NB);
            } else {
                const _Float16* b2 =
                    xt + ((size_t)(icc + k) * PHW + ((int)fcy2 + 1) * PW + (int)fcx2 + 1) * NB;
                a00 = *(const half8*)(b2);
                a10 = *(const half8*)(b2 + NB);
                a01 = *(const half8*)(b2 + PW * NB);
                a11 = *(const half8*)(b2 + (PW + 1) * NB);
            }
            haccB += a00 * hb00 + a10 * hb10 + a01 * hb01 + a11 * hb11;
        }

        #pragma unroll
        for (int b = 0; b < NB; ++b) { accT[b] += (float)haccT[b]; accB[b] += (float)haccB[b]; }
    }

    const float boxT = box_factor(boxp + c*6, wf, hf);
    const float boxB = box_factor(boxp + c*6, wf, hf + 1.f);

    const int p = (2*h2) * W + w;
    #pragma unroll
    for (int b = 0; b < NB; ++b) {
        out[((size_t)b*NC + c)*HW + p]     = accT[b] * boxT;
        out[((size_t)b*NC + c)*HW + p + W] = accB[b] * boxB;
    }
}

// ---------- fallback (round-1 kernel, no workspace needed) ----------
__global__ __launch_bounds__(256) void geom_kernel(
    const float* __restrict__ x, const float* __restrict__ geo,
    const float* __restrict__ lin, const float* __restrict__ boxp,
    float* __restrict__ out)
{
    const int c = blockIdx.x;
    const int p = blockIdx.y * blockDim.x + threadIdx.x;
    if (p >= HW) return;
    const int h = p / W;
    const int w = p - h * W;
    const float xs = 2.0f * ((float)w + 0.5f) / (float)W - 1.0f;
    const float ys = 2.0f * ((float)h + 0.5f) / (float)H - 1.0f;

    float acc[NB];
    #pragma unroll
    for (int b = 0; b < NB; ++b) acc[b] = 0.f;

    const float* gp = geo + c * ICN * 6;
    const float* lc = lin + c * ICN;

    for (int ic = 0; ic < ICN; ++ic) {
        const float t00 = gp[ic*6+0], t01 = gp[ic*6+1], t02 = gp[ic*6+2];
        const float t10 = gp[ic*6+3], t11 = gp[ic*6+4], t12 = gp[ic*6+5];
        const float l = lc[ic];
        const float gx = t00*xs + t01*ys + t02;
        const float gy = t10*xs + t11*ys + t12;
        const float ixf = ((gx + 1.f)*(float)W - 1.f) * 0.5f;
        const float iyf = ((gy + 1.f)*(float)H - 1.f) * 0.5f;
        const float ix0 = floorf(ixf), iy0 = floorf(iyf);
        const float fx = ixf - ix0, fy = iyf - iy0;
        const int cx0 = (int)ix0, cy0 = (int)iy0;
        const int cx1 = cx0 + 1,  cy1 = cy0 + 1;
        const bool vx0 = (cx0 >= 0) && (cx0 <= W-1);
        const bool vx1 = (cx1 >= 0) && (cx1 <= W-1);
        const bool vy0 = (cy0 >= 0) && (cy0 <= H-1);
        const bool vy1 = (cy1 >= 0) && (cy1 <= H-1);
        const float wx0 = 1.f - fx, wx1 = fx;
        const float wy0 = 1.f - fy, wy1 = fy;
        const float w00 = wx0*wy0 * ((vx0 && vy0) ? l : 0.f);
        const float w01 = wx0*wy1 * ((vx0 && vy1) ? l : 0.f);
        const float w10 = wx1*wy0 * ((vx1 && vy0) ? l : 0.f);
        const float w11 = wx1*wy1 * ((vx1 && vy1) ? l : 0.f);
        const int icx0 = min(max(cx0, 0), W-1);
        const int icx1 = min(max(cx1, 0), W-1);
        const int icy0 = min(max(cy0, 0), H-1);
        const int icy1 = min(max(cy1, 0), H-1);
        const int i00 = icy0*W + icx0;
        const int i01 = icy1*W + icx0;
        const int i10 = icy0*W + icx1;
        const int i11 = icy1*W + icx1;
        const float* xp = x + ic * HW;
        #pragma unroll
        for (int b = 0; b < NB; ++b) {
            const float* xb = xp + (size_t)b * ICN * HW;
            acc[b] += w00*xb[i00] + w01*xb[i01] + w10*xb[i10] + w11*xb[i11];
        }
    }

    float box = box_factor(boxp + c*6, (float)w, (float)h);
    #pragma unroll
    for (int b = 0; b < NB; ++b)
        out[((size_t)b*NC + c)*HW + p] = acc[b] * box;
}

extern "C" void kernel_launch(void* const* d_in, const int* in_sizes, int n_in,
                              void* d_out, int out_size, void* d_ws, size_t ws_size,
                              hipStream_t stream) {
    const float* x    = (const float*)d_in[0];
    const float* geo  = (const float*)d_in[1];
    const float* lin  = (const float*)d_in[2];
    const float* boxp = (const float*)d_in[3];
    float* out = (float*)d_out;

    const size_t xt_bytes  = (size_t)ICN * PHW * NB * sizeof(_Float16); // 3,444,736
    const size_t prm_off   = (xt_bytes + 255) & ~(size_t)255;
    const size_t prm_bytes = (size_t)NC * ICN * 8 * sizeof(float);      // 131,072
    if (ws_size >= prm_off + prm_bytes) {
        _Float16* xt = (_Float16*)d_ws;
        float* prm = (float*)((char*)d_ws + prm_off);
        hipLaunchKernelGGL(setup_kernel, dim3(64 + (ICN*PHW)/256), dim3(256),
                           0, stream, x, geo, lin, xt, prm);
        hipLaunchKernelGGL(geom_p_kernel, dim3(NC, 13), dim3(128),
                           0, stream, xt, prm, boxp, out);
    } else {
        hipLaunchKernelGGL(geom_kernel, dim3(NC, (HW + 255)/256), dim3(256),
                           0, stream, x, geo, lin, boxp, out);
    }
}

// Round 9
// 47.616 us; speedup vs baseline: 1.2380x; 1.2380x over previous
//
#include <hip/hip_runtime.h>

#define NB 8
#define ICN 64
#define NC 64
#define H 56
#define W 56
#define HW (H*W)
#define PH 58
#define PW 58
#define PHW (PH*PW)   // 3364

typedef __attribute__((ext_vector_type(8))) _Float16 half8;

// ---------- fused setup: prep params + transpose/pad/convert x ----------
__global__ __launch_bounds__(256) void setup_kernel(
    const float* __restrict__ x, const float* __restrict__ geo,
    const float* __restrict__ lin,
    _Float16* __restrict__ xt, float* __restrict__ prm)
{
    const int bx = blockIdx.x;
    if (bx < 64) {
        const int i = bx * 256 + threadIdx.x;        // c*ICN + ic, 16384 exact
        const float t00 = geo[i*6+0], t01 = geo[i*6+1], t02 = geo[i*6+2];
        const float t10 = geo[i*6+3], t11 = geo[i*6+4], t12 = geo[i*6+5];
        prm[i*8+0] = t00;
        prm[i*8+1] = t01;
        prm[i*8+2] = -27.5f*(t00+t01) + 28.f*t02 + 27.5f;
        prm[i*8+3] = t10;
        prm[i*8+4] = t11;
        prm[i*8+5] = -27.5f*(t10+t11) + 28.f*t12 + 27.5f;
        prm[i*8+6] = lin[i];
        prm[i*8+7] = 0.f;
    } else {
        const int id = (bx - 64) * 256 + threadIdx.x;   // ic*PHW + ph*PW + pw, 215296 exact
        const int ic  = id / PHW;
        const int rem = id - ic * PHW;
        const int ph  = rem / PW;
        const int pw  = rem - ph * PW;
        half8 v;
        #pragma unroll
        for (int b = 0; b < NB; ++b) v[b] = (_Float16)0.f;
        if (ph >= 1 && ph <= H && pw >= 1 && pw <= W) {
            const int p = (ph - 1) * W + (pw - 1);
            #pragma unroll
            for (int b = 0; b < NB; ++b)
                v[b] = (_Float16)x[(size_t)b * ICN * HW + ic * HW + p];
        }
        *(half8*)(xt + (size_t)id * NB) = v;
    }
}

__device__ __forceinline__ float box_factor(const float* bp, float wf, float hf) {
    const float xs = 2.0f * (wf + 0.5f) / (float)W - 1.0f;
    const float ys = 2.0f * (hf + 0.5f) / (float)H - 1.0f;
    const float gx = bp[0]*xs + bp[1]*ys + bp[2];
    const float gy = bp[3]*xs + bp[4]*ys + bp[5];
    const float ixf = ((gx + 1.f)*(float)W - 1.f) * 0.5f;
    const float iyf = ((gy + 1.f)*(float)H - 1.f) * 0.5f;
    const float ix0 = floorf(ixf), iy0 = floorf(iyf);
    const float fx = ixf - ix0, fy = iyf - iy0;
    const int cx0 = (int)ix0, cy0 = (int)iy0;
    const int cx1 = cx0 + 1,  cy1 = cy0 + 1;
    const bool vx0 = (cx0 >= 0) && (cx0 < W);
    const bool vx1 = (cx1 >= 0) && (cx1 < W);
    const bool vy0 = (cy0 >= 0) && (cy0 < H);
    const bool vy1 = (cy1 >= 0) && (cy1 < H);
    return (1.f-fx)*(1.f-fy)*((vx0 && vy0) ? 1.f : 0.f)
         + (1.f-fx)*fy     *((vx0 && vy1) ? 1.f : 0.f)
         + fx*(1.f-fy)     *((vx1 && vy0) ? 1.f : 0.f)
         + fx*fy           *((vx1 && vy1) ? 1.f : 0.f);
}

// ---------- main: thread owns (c,p), all 8 batches; box==0 lanes skip ic loop ----------
__global__ __launch_bounds__(256) void geom_h5_kernel(
    const _Float16* __restrict__ xt, // (IC, 58, 58, B)
    const float* __restrict__ prm,   // (C, IC, 8) folded params
    const float* __restrict__ boxp,  // (C, 2, 3)
    float* __restrict__ out)         // (B, C, H, W)
{
    const int c = blockIdx.x;
    const int p = blockIdx.y * 256 + threadIdx.x;    // 13 blocks -> 3328 slots
    if (p >= HW) return;
    const int h = p / W;
    const int w = p - h * W;
    const float wf = (float)w, hf = (float)h;

    // box coverage factor FIRST: lanes (and whole waves) with box==0 skip the
    // entire 64-ic gather loop (exec-masked loads don't consume TA addresses).
    const float box = box_factor(boxp + c*6, wf, hf);

    float acc[NB];
    #pragma unroll
    for (int b = 0; b < NB; ++b) acc[b] = 0.f;

    if (box != 0.f) {
        const float* pp = prm + (size_t)c * ICN * 8;

        for (int icc = 0; icc < ICN; icc += 4) {
            half8 hacc;
            #pragma unroll
            for (int b = 0; b < NB; ++b) hacc[b] = (_Float16)0.f;

            #pragma unroll
            for (int k = 0; k < 4; ++k) {
                const float* q = pp + (icc + k) * 8;     // block-uniform -> s_load
                const float ixf = fmaf(q[0], wf, fmaf(q[1], hf, q[2]));
                const float iyf = fmaf(q[3], wf, fmaf(q[4], hf, q[5]));
                const float l   = q[6];

                const float fcx0 = fminf(fmaxf(floorf(ixf), -1.f), 55.f);
                const float fcy0 = fminf(fmaxf(floorf(iyf), -1.f), 55.f);
                const float wx0 = fmaxf(0.f, 1.f - fabsf(ixf - fcx0));
                const float wx1 = fmaxf(0.f, 1.f - fabsf(ixf - fcx0 - 1.f));
                const float wy0 = fmaxf(0.f, 1.f - fabsf(iyf - fcy0));
                const float wy1 = fmaxf(0.f, 1.f - fabsf(iyf - fcy0 - 1.f));
                const float wy0l = wy0 * l, wy1l = wy1 * l;

                const _Float16 hw00 = (_Float16)(wx0 * wy0l);
                const _Float16 hw10 = (_Float16)(wx1 * wy0l);
                const _Float16 hw01 = (_Float16)(wx0 * wy1l);
                const _Float16 hw11 = (_Float16)(wx1 * wy1l);

                const int i00 = ((int)fcy0) * PW + (int)fcx0 + (PW + 1); // padded index
                const _Float16* base = xt + ((size_t)(icc + k) * PHW + i00) * NB;

                const half8 v00 = *(const half8*)(base);
                const half8 v10 = *(const half8*)(base + NB);            // +16B
                const half8 v01 = *(const half8*)(base + PW * NB);       // +928B
                const half8 v11 = *(const half8*)(base + (PW + 1) * NB); // +944B

                hacc += v00 * hw00 + v10 * hw10 + v01 * hw01 + v11 * hw11;
            }

            #pragma unroll
            for (int b = 0; b < NB; ++b) acc[b] += (float)hacc[b];
        }
    }

    #pragma unroll
    for (int b = 0; b < NB; ++b)
        out[((size_t)b*NC + c)*HW + p] = acc[b] * box;
}

// ---------- fallback (round-1 kernel, no workspace needed) ----------
__global__ __launch_bounds__(256) void geom_kernel(
    const float* __restrict__ x, const float* __restrict__ geo,
    const float* __restrict__ lin, const float* __restrict__ boxp,
    float* __restrict__ out)
{
    const int c = blockIdx.x;
    const int p = blockIdx.y * blockDim.x + threadIdx.x;
    if (p >= HW) return;
    const int h = p / W;
    const int w = p - h * W;
    const float xs = 2.0f * ((float)w + 0.5f) / (float)W - 1.0f;
    const float ys = 2.0f * ((float)h + 0.5f) / (float)H - 1.0f;

    float acc[NB];
    #pragma unroll
    for (int b = 0; b < NB; ++b) acc[b] = 0.f;

    const float* gp = geo + c * ICN * 6;
    const float* lc = lin + c * ICN;

    for (int ic = 0; ic < ICN; ++ic) {
        const float t00 = gp[ic*6+0], t01 = gp[ic*6+1], t02 = gp[ic*6+2];
        const float t10 = gp[ic*6+3], t11 = gp[ic*6+4], t12 = gp[ic*6+5];
        const float l = lc[ic];
        const float gx = t00*xs + t01*ys + t02;
        const float gy = t10*xs + t11*ys + t12;
        const float ixf = ((gx + 1.f)*(float)W - 1.f) * 0.5f;
        const float iyf = ((gy + 1.f)*(float)H - 1.f) * 0.5f;
        const float ix0 = floorf(ixf), iy0 = floorf(iyf);
        const float fx = ixf - ix0, fy = iyf - iy0;
        const int cx0 = (int)ix0, cy0 = (int)iy0;
        const int cx1 = cx0 + 1,  cy1 = cy0 + 1;
        const bool vx0 = (cx0 >= 0) && (cx0 <= W-1);
        const bool vx1 = (cx1 >= 0) && (cx1 <= W-1);
        const bool vy0 = (cy0 >= 0) && (cy0 <= H-1);
        const bool vy1 = (cy1 >= 0) && (cy1 <= H-1);
        const float wx0 = 1.f - fx, wx1 = fx;
        const float wy0 = 1.f - fy, wy1 = fy;
        const float w00 = wx0*wy0 * ((vx0 && vy0) ? l : 0.f);
        const float w01 = wx0*wy1 * ((vx0 && vy1) ? l : 0.f);
        const float w10 = wx1*wy0 * ((vx1 && vy0) ? l : 0.f);
        const float w11 = wx1*wy1 * ((vx1 && vy1) ? l : 0.f);
        const int icx0 = min(max(cx0, 0), W-1);
        const int icx1 = min(max(cx1, 0), W-1);
        const int icy0 = min(max(cy0, 0), H-1);
        const int icy1 = min(max(cy1, 0), H-1);
        const int i00 = icy0*W + icx0;
        const int i01 = icy1*W + icx0;
        const int i10 = icy0*W + icx1;
        const int i11 = icy1*W + icx1;
        const float* xp = x + ic * HW;
        #pragma unroll
        for (int b = 0; b < NB; ++b) {
            const float* xb = xp + (size_t)b * ICN * HW;
            acc[b] += w00*xb[i00] + w01*xb[i01] + w10*xb[i10] + w11*xb[i11];
        }
    }

    float box = box_factor(boxp + c*6, (float)w, (float)h);
    #pragma unroll
    for (int b = 0; b < NB; ++b)
        out[((size_t)b*NC + c)*HW + p] = acc[b] * box;
}

extern "C" void kernel_launch(void* const* d_in, const int* in_sizes, int n_in,
                              void* d_out, int out_size, void* d_ws, size_t ws_size,
                              hipStream_t stream) {
    const float* x    = (const float*)d_in[0];
    const float* geo  = (const float*)d_in[1];
    const float* lin  = (const float*)d_in[2];
    const float* boxp = (const float*)d_in[3];
    float* out = (float*)d_out;

    const size_t xt_bytes  = (size_t)ICN * PHW * NB * sizeof(_Float16); // 3,444,736
    const size_t prm_off   = (xt_bytes + 255) & ~(size_t)255;
    const size_t prm_bytes = (size_t)NC * ICN * 8 * sizeof(float);      // 131,072
    if (ws_size >= prm_off + prm_bytes) {
        _Float16* xt = (_Float16*)d_ws;
        float* prm = (float*)((char*)d_ws + prm_off);
        hipLaunchKernelGGL(setup_kernel, dim3(64 + (ICN*PHW)/256), dim3(256),
                           0, stream, x, geo, lin, xt, prm);
        hipLaunchKernelGGL(geom_h5_kernel, dim3(NC, (HW + 255)/256), dim3(256),
                           0, stream, xt, prm, boxp, out);
    } else {
        hipLaunchKernelGGL(geom_kernel, dim3(NC, (HW + 255)/256), dim3(256),
                           0, stream, x, geo, lin, boxp, out);
    }
}